// Round 13
// baseline (174.381 us; speedup 1.0000x reference)
//
#include <hip/hip_runtime.h>
#include <hip/hip_fp16.h>
#include <math.h>

#define HWSZ 65536   // 256*256
#define IMGH 256
#define IMGW 256

typedef _Float16 half8 __attribute__((ext_vector_type(8)));
typedef float f32x4 __attribute__((ext_vector_type(4)));

__device__ inline unsigned short f2bf(float f) {
    unsigned u = __float_as_uint(f);
    return (unsigned short)((u + 0x7fffu + ((u >> 16) & 1u)) >> 16);
}
__device__ inline unsigned short f2h(float f) {
    __half h = __float2half(f);
    return __half_as_ushort(h);
}
__device__ inline __half2 duph2(unsigned s) {
    union { unsigned u; __half2 h; } c;
    c.u = (s & 0xffffu) * 0x10001u;
    return c.h;
}
__device__ inline void hacc(const uint4& q, __half2 w, __half2* v) {
    const __half2* h = (const __half2*)&q;
    v[0] = __hfma2(h[0], w, v[0]);
    v[1] = __hfma2(h[1], w, v[1]);
    v[2] = __hfma2(h[2], w, v[2]);
    v[3] = __hfma2(h[3], w, v[3]);
}

// ---------------- K0a: pack MFMA A-fragments (fp16) ----------------
__global__ void prep_weights(const float* __restrict__ w_off,
                             const float* __restrict__ w,
                             unsigned short* __restrict__ wApack,
                             unsigned short* __restrict__ wOffPack) {
    int i = blockIdx.x * 256 + threadIdx.x;
    if (i < 36864) {
        int e = i;
        int j = e & 7, lane = (e >> 3) & 63, kk = (e >> 9) & 1;
        int t2 = e >> 10;
        int tap = t2 % 9, g = t2 / 9;
        int o = g * 16 + (lane & 15);
        int c = kk * 32 + ((lane >> 4) & 3) * 8 + j;
        wApack[e] = f2h(w[(o * 64 + c) * 9 + tap]);
    } else if (i < 36864 + 18432) {
        int e = i - 36864;
        int j = e & 7, lane = (e >> 3) & 63, kk = (e >> 9) & 1;
        int t2 = e >> 10;
        int tap = t2 % 9, mt = t2 / 9;
        int d = mt * 16 + (lane & 15);
        int c = kk * 32 + ((lane >> 4) & 3) * 8 + j;
        float v = (d < 27) ? w_off[(d * 64 + c) * 9 + tap] : 0.f;
        wOffPack[e] = f2h(v);
    }
}

// ---------------- K0b: x NCHW fp32 -> NHWC fp16 ----------------
__global__ __launch_bounds__(256) void transpose_x(const float* __restrict__ x,
                                                   unsigned short* __restrict__ xT) {
    __shared__ float tile[64 * 65];
    int blk = blockIdx.x;              // 2048 = 2 * 1024
    int b = blk >> 10;
    int p0 = (blk & 1023) * 64;
    int t = threadIdx.x;
    const float* xb = x + (size_t)b * 64 * HWSZ;
    unsigned short* xTb = xT + (size_t)b * HWSZ * 64;
    int pp = t & 63;
    int c0r = t >> 6;
#pragma unroll
    for (int i = 0; i < 16; ++i) {
        int c = c0r + 4 * i;
        tile[c * 65 + pp] = xb[(size_t)c * HWSZ + p0 + pp];
    }
    __syncthreads();
#pragma unroll
    for (int it = 0; it < 2; ++it) {
        int item = t + it * 256;       // 512 items
        int p = item >> 3;
        int c0 = (item & 7) * 8;
        uint4 ow;
        ow.x = f2h(tile[(c0 + 0) * 65 + p]) | ((unsigned)f2h(tile[(c0 + 1) * 65 + p]) << 16);
        ow.y = f2h(tile[(c0 + 2) * 65 + p]) | ((unsigned)f2h(tile[(c0 + 3) * 65 + p]) << 16);
        ow.z = f2h(tile[(c0 + 4) * 65 + p]) | ((unsigned)f2h(tile[(c0 + 5) * 65 + p]) << 16);
        ow.w = f2h(tile[(c0 + 6) * 65 + p]) | ((unsigned)f2h(tile[(c0 + 7) * 65 + p]) << 16);
        *(uint4*)&xTb[(size_t)(p0 + p) * 64 + c0] = ow;
    }
}

// ---------------- K2: FUSED conv + deformable sample + MFMA, HIGH-OCCUPANCY ----------------
// 512 thr, 16x8 tile, NO LDS halo: all x reads from global (L2 via XCD swizzle).
// LDS = om_s (13.8 KB, overlaid by prmi/prmw) + bstats. launch_bounds(512,4):
// VGPR cap 128 -> allocator lands ~56-72 arch VGPRs, NO spills (R10-proven);
// occupancy then VGPR-set (up to 8 waves/SIMD), not bound-capped.
__global__ __launch_bounds__(512, 4) void dcn_main(const unsigned short* __restrict__ xT,
                                                   const unsigned short* __restrict__ wApack,
                                                   const unsigned short* __restrict__ wOffPack,
                                                   const float* __restrict__ b_off,
                                                   unsigned short* __restrict__ preout,
                                                   float* __restrict__ stats) {
    __shared__ float om_s[27 * 128];   // 13824 B; overlaid by prmi/prmw after phase 2
    __shared__ float bstats[128];      // 512 B
    unsigned* prmi = (unsigned*)om_s;          // [9][128]  (4608 B)
    uint2* prmw_s = (uint2*)(om_s + 1152);     // [9][128]  (9216 B)
    int bid = blockIdx.x;              // 1024
    int blk = ((bid & 7) << 7) | (bid >> 3);   // XCD-chunked swizzle (1024%8==0)
    int b = blk >> 9;
    int tb = blk & 511;                // 16 row-tiles x 32 col-tiles
    int ty = tb >> 5, tx = tb & 31;
    int h0 = ty * 16, w0 = tx * 8;
    int t = threadIdx.x;
    const char* xbb = (const char*)(xT + (size_t)b * HWSZ * 64);
    int lane = t & 63;
    int wid = t >> 6;                  // 0..7
    int lp = lane & 15;
    int lhi = lane >> 4;
    unsigned lhi16 = (unsigned)(lhi << 4);
    int p = wid * 16 + lp;             // 0..127 ; pixel (p>>3, p&7) in 16x8 tile

    if (t < 128) bstats[t] = 0.f;

    // ---- phase 1: offset conv via MFMA, x from global -> om_s (+b_off) ----
    {
        int mt = wid & 1;
        const half8* wp = (const half8*)wOffPack;
        half8 hz = {0, 0, 0, 0, 0, 0, 0, 0};
        f32x4 z0 = {0.f, 0.f, 0.f, 0.f};
#pragma unroll
        for (int hf = 0; hf < 2; ++hf) {
            int nt = (wid >> 1) + hf * 4;
            int pp = nt * 16 + lp;
            int pr = pp >> 3, pc = pp & 7;
            f32x4 oa = z0;
#pragma unroll
            for (int tap = 0; tap < 9; ++tap) {
                int dy = tap / 3, dx = tap - dy * 3;
                int y = h0 + pr + dy - 1, xx = w0 + pc + dx - 1;
                bool inb = ((unsigned)y < 256u) && ((unsigned)xx < 256u);
                const char* ga = xbb + (((size_t)((y << 8) + xx)) << 7) + lhi16;
                half8 b0 = inb ? *(const half8*)ga : hz;
                half8 b1 = inb ? *(const half8*)(ga + 64) : hz;
                half8 wa0 = wp[((mt * 9 + tap) * 2 + 0) * 64 + lane];
                half8 wa1 = wp[((mt * 9 + tap) * 2 + 1) * 64 + lane];
                oa = __builtin_amdgcn_mfma_f32_16x16x32_f16(wa0, b0, oa, 0, 0, 0);
                oa = __builtin_amdgcn_mfma_f32_16x16x32_f16(wa1, b1, oa, 0, 0, 0);
            }
#pragma unroll
            for (int jj = 0; jj < 4; ++jj) {
                int d = mt * 16 + lhi * 4 + jj;
                if (d < 27) om_s[d * 128 + pp] = oa[jj] + b_off[d];
            }
        }
    }
    __syncthreads();

    // ---- phase 2: cooperative params (read om_s -> regs -> barrier -> overlay write) ----
    // enc = 4 clamped coords packed: y0c | y1c<<8 | x0c<<16 | x1c<<24 (branch-free gathers)
#define PARAMS(I, EOUT, WOUT)                                                 \
    {                                                                         \
        int i_ = (I);                                                         \
        int tp_ = i_ >> 7, pp_ = i_ & 127;                                    \
        int hh_ = h0 + (pp_ >> 3), wc_ = w0 + (pp_ & 7);                      \
        float offy = om_s[tp_ * 128 + pp_];                                   \
        float offx = om_s[(tp_ + 9) * 128 + pp_];                             \
        float mraw = om_s[(tp_ + 18) * 128 + pp_];                            \
        float m_ = 1.f / (1.f + __expf(-mraw));                               \
        float pyf = (float)(hh_ + tp_ / 3 - 1) + offy;                        \
        float pxf = (float)(wc_ + tp_ % 3 - 1) + offx;                        \
        float y0f = floorf(pyf), x0f = floorf(pxf);                           \
        float wy = pyf - y0f, wx = pxf - x0f;                                 \
        int y0_ = (int)y0f, x0_ = (int)x0f;                                   \
        int y1_ = y0_ + 1, x1_ = x0_ + 1;                                     \
        float vy0 = (y0_ >= 0 && y0_ < IMGH) ? 1.f : 0.f;                     \
        float vy1 = (y1_ >= 0 && y1_ < IMGH) ? 1.f : 0.f;                     \
        float vx0 = (x0_ >= 0 && x0_ < IMGW) ? 1.f : 0.f;                     \
        float vx1 = (x1_ >= 0 && x1_ < IMGW) ? 1.f : 0.f;                     \
        float w00 = (1.f - wy) * (1.f - wx) * m_ * vy0 * vx0;                 \
        float w01 = (1.f - wy) * wx * m_ * vy0 * vx1;                         \
        float w10 = wy * (1.f - wx) * m_ * vy1 * vx0;                         \
        float w11 = wy * wx * m_ * vy1 * vx1;                                 \
        WOUT = make_uint2((unsigned)f2h(w00) | ((unsigned)f2h(w01) << 16),    \
                          (unsigned)f2h(w10) | ((unsigned)f2h(w11) << 16));   \
        unsigned y0c = (unsigned)min(max(y0_, 0), 255);                       \
        unsigned y1c = (unsigned)min(max(y1_, 0), 255);                       \
        unsigned x0c = (unsigned)min(max(x0_, 0), 255);                       \
        unsigned x1c = (unsigned)min(max(x1_, 0), 255);                       \
        EOUT = y0c | (y1c << 8) | (x0c << 16) | (x1c << 24);                  \
    }
    {
        unsigned pe0, pe1, pe2 = 0;
        uint2 pw0 = make_uint2(0, 0), pw1 = pw0, pw2 = pw0;
        PARAMS(t, pe0, pw0);
        PARAMS(t + 512, pe1, pw1);
        if (t < 128) PARAMS(t + 1024, pe2, pw2);
        __syncthreads();               // all om_s reads done
        prmi[t] = pe0;        prmw_s[t] = pw0;
        prmi[t + 512] = pe1;  prmw_s[t + 512] = pw1;
        if (t < 128) { prmi[t + 1024] = pe2; prmw_s[t + 1024] = pw2; }
    }
#undef PARAMS
    __syncthreads();
    // ---- phase 3: tap loop — waves independent, branch-free global gathers ----

    f32x4 z = {0.f, 0.f, 0.f, 0.f};
    f32x4 acc[4] = {z, z, z, z};
    const half8* ap = (const half8*)wApack;
    uint4 q[4][2];                     // [corner][kk]

#define LOADC(E)                                                              \
    {                                                                         \
        unsigned e_ = (E);                                                    \
        unsigned r0_ = (e_ & 255u) << 8, r1_ = ((e_ >> 8) & 255u) << 8;       \
        unsigned c0_ = (e_ >> 16) & 255u, c1_ = e_ >> 24;                     \
        const char* g00 = xbb + ((((size_t)(r0_ + c0_)) << 7) | lhi16);       \
        const char* g01 = xbb + ((((size_t)(r0_ + c1_)) << 7) | lhi16);       \
        const char* g10 = xbb + ((((size_t)(r1_ + c0_)) << 7) | lhi16);       \
        const char* g11 = xbb + ((((size_t)(r1_ + c1_)) << 7) | lhi16);       \
        q[0][0] = *(const uint4*)g00; q[0][1] = *(const uint4*)(g00 + 64);    \
        q[1][0] = *(const uint4*)g01; q[1][1] = *(const uint4*)(g01 + 64);    \
        q[2][0] = *(const uint4*)g10; q[2][1] = *(const uint4*)(g10 + 64);    \
        q[3][0] = *(const uint4*)g11; q[3][1] = *(const uint4*)(g11 + 64);    \
    }

#pragma unroll
    for (int tap = 0; tap < 9; ++tap) {
        unsigned pi = prmi[tap * 128 + p];
        uint2 ww = prmw_s[tap * 128 + p];
        LOADC(pi);
        __half2 W00 = duph2(ww.x), W01 = duph2(ww.x >> 16);
        __half2 W10 = duph2(ww.y), W11 = duph2(ww.y >> 16);
        union HV { __half2 h2[4]; half8 h8; } V0, V1;
        __half2 z2 = __float2half2_rn(0.f);
#pragma unroll
        for (int j = 0; j < 4; ++j) { V0.h2[j] = z2; V1.h2[j] = z2; }
        hacc(q[0][0], W00, V0.h2); hacc(q[0][1], W00, V1.h2);
        hacc(q[1][0], W01, V0.h2); hacc(q[1][1], W01, V1.h2);
        hacc(q[2][0], W10, V0.h2); hacc(q[2][1], W10, V1.h2);
        hacc(q[3][0], W11, V0.h2); hacc(q[3][1], W11, V1.h2);
        half8 b0 = V0.h8, b1 = V1.h8;
        __builtin_amdgcn_s_setprio(1);
#pragma unroll
        for (int g2 = 0; g2 < 4; ++g2) {
            half8 a0 = ap[((g2 * 9 + tap) * 2 + 0) * 64 + lane];
            half8 a1 = ap[((g2 * 9 + tap) * 2 + 1) * 64 + lane];
            acc[g2] = __builtin_amdgcn_mfma_f32_16x16x32_f16(a0, b0, acc[g2], 0, 0, 0);
            acc[g2] = __builtin_amdgcn_mfma_f32_16x16x32_f16(a1, b1, acc[g2], 0, 0, 0);
        }
        __builtin_amdgcn_s_setprio(0);
    }
#undef LOADC

    // epilogue: preout (bf16, NCHW)
    unsigned short* pob = preout + (size_t)b * 64 * HWSZ;
    int gp = (h0 + (p >> 3)) * IMGW + w0 + (p & 7);
#pragma unroll
    for (int g2 = 0; g2 < 4; ++g2) {
#pragma unroll
        for (int jj = 0; jj < 4; ++jj) {
            int o = g2 * 16 + lhi * 4 + jj;
            pob[(size_t)o * HWSZ + gp] = f2bf(acc[g2][jj]);
        }
    }
    // BN partial stats
#pragma unroll
    for (int g2 = 0; g2 < 4; ++g2) {
#pragma unroll
        for (int jj = 0; jj < 4; ++jj) {
            float s1 = acc[g2][jj];
            float s2 = s1 * s1;
#pragma unroll
            for (int mask = 1; mask < 16; mask <<= 1) {
                s1 += __shfl_xor(s1, mask);
                s2 += __shfl_xor(s2, mask);
            }
            if (lp == 0) {
                int o = g2 * 16 + lhi * 4 + jj;
                atomicAdd(&bstats[o], s1);
                atomicAdd(&bstats[64 + o], s2);
            }
        }
    }
    __syncthreads();
    if (t < 128) atomicAdd(&stats[t], bstats[t]);
}

// ---------------- K3: normalize + relu + residual ----------------
__global__ __launch_bounds__(256) void bn_finalize(const float* __restrict__ stats,
                                                   const float* __restrict__ gamma,
                                                   const float* __restrict__ beta,
                                                   const float* __restrict__ x,
                                                   const unsigned short* __restrict__ preout,
                                                   float* __restrict__ out) {
    int i = blockIdx.x * 256 + threadIdx.x;     // uint4 idx over 8.4M bf16
    int e0 = i * 8;
    int o = (e0 >> 16) & 63;
    const float inv_n = 1.f / 131072.f;
    float mean = stats[o] * inv_n;
    float var = stats[64 + o] * inv_n - mean * mean;
    float rstd = rsqrtf(var + 1e-5f);
    float g = gamma[o] * rstd;
    float bb = beta[o] - mean * g;
    uint4 q = ((const uint4*)preout)[i];
    float4 x0 = ((const float4*)x)[i * 2];
    float4 x1 = ((const float4*)x)[i * 2 + 1];
    float4 r0, r1;
    r0.x = fmaxf(__uint_as_float(q.x << 16) * g + bb, 0.f) + x0.x;
    r0.y = fmaxf(__uint_as_float(q.x & 0xffff0000u) * g + bb, 0.f) + x0.y;
    r0.z = fmaxf(__uint_as_float(q.y << 16) * g + bb, 0.f) + x0.z;
    r0.w = fmaxf(__uint_as_float(q.y & 0xffff0000u) * g + bb, 0.f) + x0.w;
    r1.x = fmaxf(__uint_as_float(q.z << 16) * g + bb, 0.f) + x1.x;
    r1.y = fmaxf(__uint_as_float(q.z & 0xffff0000u) * g + bb, 0.f) + x1.y;
    r1.z = fmaxf(__uint_as_float(q.w << 16) * g + bb, 0.f) + x1.z;
    r1.w = fmaxf(__uint_as_float(q.w & 0xffff0000u) * g + bb, 0.f) + x1.w;
    ((float4*)out)[i * 2] = r0;
    ((float4*)out)[i * 2 + 1] = r1;
}

extern "C" void kernel_launch(void* const* d_in, const int* in_sizes, int n_in,
                              void* d_out, int out_size, void* d_ws, size_t ws_size,
                              hipStream_t stream) {
    const float* x     = (const float*)d_in[0];
    const float* w_off = (const float*)d_in[1];
    const float* b_off = (const float*)d_in[2];
    const float* w     = (const float*)d_in[3];
    const float* gamma = (const float*)d_in[5];
    const float* beta  = (const float*)d_in[6];
    float* out = (float*)d_out;
    char* wsb = (char*)d_ws;

    unsigned short* xT       = (unsigned short*)wsb;                    // 16,777,216 B (fp16)
    unsigned short* preout   = (unsigned short*)(wsb + 16777216);       // 16,777,216 B (bf16)
    unsigned short* wApack   = (unsigned short*)(wsb + 33554432);       // 73,728 B (fp16)
    unsigned short* wOffPack = (unsigned short*)(wsb + 33628160);       // 36,864 B (fp16)
    float*          stats    = (float*)(wsb + 33665024);                // 512 B

    hipMemsetAsync(stats, 0, 512, stream);
    prep_weights<<<216, 256, 0, stream>>>(w_off, w, wApack, wOffPack);
    transpose_x<<<2048, 256, 0, stream>>>(x, xT);
    dcn_main<<<1024, 512, 0, stream>>>(xT, wApack, wOffPack, b_off, preout, stats);
    bn_finalize<<<4096, 256, 0, stream>>>(stats, gamma, beta, x, preout, out);
}

// Round 14
// 93.090 us; speedup vs baseline: 1.8732x; 1.8732x over previous
//
#include <hip/hip_runtime.h>
#include <hip/hip_fp16.h>
#include <math.h>

#define HWSZ 65536   // 256*256
#define IMGH 256
#define IMGW 256

typedef _Float16 half8 __attribute__((ext_vector_type(8)));
typedef float f32x4 __attribute__((ext_vector_type(4)));

__device__ inline unsigned short f2bf(float f) {
    unsigned u = __float_as_uint(f);
    return (unsigned short)((u + 0x7fffu + ((u >> 16) & 1u)) >> 16);
}
__device__ inline unsigned short f2h(float f) {
    __half h = __float2half(f);
    return __half_as_ushort(h);
}
__device__ inline __half2 duph2(unsigned s) {
    union { unsigned u; __half2 h; } c;
    c.u = (s & 0xffffu) * 0x10001u;
    return c.h;
}
__device__ inline void hacc(const uint4& q, __half2 w, __half2* v) {
    const __half2* h = (const __half2*)&q;
    v[0] = __hfma2(h[0], w, v[0]);
    v[1] = __hfma2(h[1], w, v[1]);
    v[2] = __hfma2(h[2], w, v[2]);
    v[3] = __hfma2(h[3], w, v[3]);
}

// ---------------- K0a: pack MFMA A-fragments (fp16) ----------------
__global__ void prep_weights(const float* __restrict__ w_off,
                             const float* __restrict__ w,
                             unsigned short* __restrict__ wApack,
                             unsigned short* __restrict__ wOffPack) {
    int i = blockIdx.x * 256 + threadIdx.x;
    if (i < 36864) {
        int e = i;
        int j = e & 7, lane = (e >> 3) & 63, kk = (e >> 9) & 1;
        int t2 = e >> 10;
        int tap = t2 % 9, g = t2 / 9;
        int o = g * 16 + (lane & 15);
        int c = kk * 32 + ((lane >> 4) & 3) * 8 + j;
        wApack[e] = f2h(w[(o * 64 + c) * 9 + tap]);
    } else if (i < 36864 + 18432) {
        int e = i - 36864;
        int j = e & 7, lane = (e >> 3) & 63, kk = (e >> 9) & 1;
        int t2 = e >> 10;
        int tap = t2 % 9, mt = t2 / 9;
        int d = mt * 16 + (lane & 15);
        int c = kk * 32 + ((lane >> 4) & 3) * 8 + j;
        float v = (d < 27) ? w_off[(d * 64 + c) * 9 + tap] : 0.f;
        wOffPack[e] = f2h(v);
    }
}

// ---------------- K0b: x NCHW fp32 -> NHWC fp16 ----------------
__global__ __launch_bounds__(256) void transpose_x(const float* __restrict__ x,
                                                   unsigned short* __restrict__ xT) {
    __shared__ float tile[64 * 65];
    int blk = blockIdx.x;              // 2048 = 2 * 1024
    int b = blk >> 10;
    int p0 = (blk & 1023) * 64;
    int t = threadIdx.x;
    const float* xb = x + (size_t)b * 64 * HWSZ;
    unsigned short* xTb = xT + (size_t)b * HWSZ * 64;
    int pp = t & 63;
    int c0r = t >> 6;
#pragma unroll
    for (int i = 0; i < 16; ++i) {
        int c = c0r + 4 * i;
        tile[c * 65 + pp] = xb[(size_t)c * HWSZ + p0 + pp];
    }
    __syncthreads();
#pragma unroll
    for (int it = 0; it < 2; ++it) {
        int item = t + it * 256;       // 512 items
        int p = item >> 3;
        int c0 = (item & 7) * 8;
        uint4 ow;
        ow.x = f2h(tile[(c0 + 0) * 65 + p]) | ((unsigned)f2h(tile[(c0 + 1) * 65 + p]) << 16);
        ow.y = f2h(tile[(c0 + 2) * 65 + p]) | ((unsigned)f2h(tile[(c0 + 3) * 65 + p]) << 16);
        ow.z = f2h(tile[(c0 + 4) * 65 + p]) | ((unsigned)f2h(tile[(c0 + 5) * 65 + p]) << 16);
        ow.w = f2h(tile[(c0 + 6) * 65 + p]) | ((unsigned)f2h(tile[(c0 + 7) * 65 + p]) << 16);
        *(uint4*)&xTb[(size_t)(p0 + p) * 64 + c0] = ow;
    }
}

// ---------------- K2: FUSED offset-conv + deformable sample + MFMA einsum ----------------
// 512 thr, 16x8 tile. Halo 26x18 cells x 64ch fp16 (chunk-XOR swizzled).
// Phase1: conv via MFMA -> om_s (LDS). Phase2: params cooperatively, overlaid on om_s.
// Phase3: barrier-free tap loop with prm 2-deep + q 1-deep prefetch pipeline.
__global__ __launch_bounds__(512, 4) void dcn_main(const unsigned short* __restrict__ xT,
                                                   const unsigned short* __restrict__ wApack,
                                                   const unsigned short* __restrict__ wOffPack,
                                                   const float* __restrict__ b_off,
                                                   unsigned short* __restrict__ preout,
                                                   float* __restrict__ stats) {
    __shared__ uint4 haloBuf[3744];    // 468 cells x 128B = 59904 B
    __shared__ float om_s[27 * 128];   // 13824 B; overlaid by prmi/prmw after phase 2
    __shared__ float bstats[128];      // 512 B
    char* halo = (char*)haloBuf;
    unsigned* prmi = (unsigned*)om_s;          // [9][128]  (4608 B)
    uint2* prmw_s = (uint2*)(om_s + 1152);     // [9][128]  (9216 B)
    int bid = blockIdx.x;              // 1024
    int blk = ((bid & 7) << 7) | (bid >> 3);   // XCD-chunked swizzle (1024%8==0)
    int b = blk >> 9;
    int tb = blk & 511;                // 16 row-tiles x 32 col-tiles
    int ty = tb >> 5, tx = tb & 31;
    int h0 = ty * 16, w0 = tx * 8;
    int t = threadIdx.x;
    const char* xbb = (const char*)(xT + (size_t)b * HWSZ * 64);
    int lane = t & 63;
    int wid = t >> 6;                  // 0..7
    int lp = lane & 15;
    int lhi = lane >> 4;
    unsigned lhi16 = (unsigned)(lhi << 4);
    int p = wid * 16 + lp;             // 0..127 ; pixel (p>>3, p&7) in 16x8 tile
    int hb = h0 - 5, wb = w0 - 5;

    if (t < 128) bstats[t] = 0.f;

    // ---- phase 0: stage halo (468 cells x 8 chunks; chunk ch at slot ch^(cell&7)) ----
    for (int i = t; i < 3744; i += 512) {
        int cell = i >> 3;
        int ch = i & 7;
        int r = cell / 18, c = cell - r * 18;
        int y = hb + r, xx = wb + c;
        uint4 v = {0u, 0u, 0u, 0u};
        if ((unsigned)y < 256u && (unsigned)xx < 256u)
            v = *(const uint4*)(xbb + ((size_t)((y << 8) + xx) << 7) + (ch << 4));
        *(uint4*)(halo + (cell << 7) + ((ch ^ (cell & 7)) << 4)) = v;
    }
    __syncthreads();

    // ---- phase 1: offset conv via MFMA from halo -> om_s (+b_off) ----
    {
        int mt = wid & 1;
        const half8* wp = (const half8*)wOffPack;
        f32x4 z0 = {0.f, 0.f, 0.f, 0.f};
#pragma unroll
        for (int hf = 0; hf < 2; ++hf) {
            int nt = (wid >> 1) + hf * 4;
            int pp = nt * 16 + lp;
            int pr = pp >> 3, pc = pp & 7;
            f32x4 oa = z0;
#pragma unroll
            for (int tap = 0; tap < 9; ++tap) {
                int dy = tap / 3, dx = tap - dy * 3;
                int cell = (pr + dy + 4) * 18 + (pc + dx + 4);
                unsigned ad = (((unsigned)cell << 7) | (((unsigned)cell & 7) << 4)) ^ lhi16;
                half8 b0 = *(const half8*)(halo + ad);
                half8 b1 = *(const half8*)(halo + (ad ^ 64u));
                half8 wa0 = wp[((mt * 9 + tap) * 2 + 0) * 64 + lane];
                half8 wa1 = wp[((mt * 9 + tap) * 2 + 1) * 64 + lane];
                oa = __builtin_amdgcn_mfma_f32_16x16x32_f16(wa0, b0, oa, 0, 0, 0);
                oa = __builtin_amdgcn_mfma_f32_16x16x32_f16(wa1, b1, oa, 0, 0, 0);
            }
#pragma unroll
            for (int jj = 0; jj < 4; ++jj) {
                int d = mt * 16 + lhi * 4 + jj;
                if (d < 27) om_s[d * 128 + pp] = oa[jj] + b_off[d];
            }
        }
    }
    __syncthreads();

    // ---- phase 2: cooperative params (read om_s -> regs -> barrier -> overlay write) ----
#define PARAMS(I, EOUT, WOUT)                                                 \
    {                                                                         \
        int i_ = (I);                                                         \
        int tp_ = i_ >> 7, pp_ = i_ & 127;                                    \
        int hh_ = h0 + (pp_ >> 3), wc_ = w0 + (pp_ & 7);                      \
        float offy = om_s[tp_ * 128 + pp_];                                   \
        float offx = om_s[(tp_ + 9) * 128 + pp_];                             \
        float mraw = om_s[(tp_ + 18) * 128 + pp_];                            \
        float m_ = 1.f / (1.f + __expf(-mraw));                               \
        float pyf = (float)(hh_ + tp_ / 3 - 1) + offy;                        \
        float pxf = (float)(wc_ + tp_ % 3 - 1) + offx;                        \
        float y0f = floorf(pyf), x0f = floorf(pxf);                           \
        float wy = pyf - y0f, wx = pxf - x0f;                                 \
        int y0_ = (int)y0f, x0_ = (int)x0f;                                   \
        int y1_ = y0_ + 1, x1_ = x0_ + 1;                                     \
        float vy0 = (y0_ >= 0 && y0_ < IMGH) ? 1.f : 0.f;                     \
        float vy1 = (y1_ >= 0 && y1_ < IMGH) ? 1.f : 0.f;                     \
        float vx0 = (x0_ >= 0 && x0_ < IMGW) ? 1.f : 0.f;                     \
        float vx1 = (x1_ >= 0 && x1_ < IMGW) ? 1.f : 0.f;                     \
        float w00 = (1.f - wy) * (1.f - wx) * m_ * vy0 * vx0;                 \
        float w01 = (1.f - wy) * wx * m_ * vy0 * vx1;                         \
        float w10 = wy * (1.f - wx) * m_ * vy1 * vx0;                         \
        float w11 = wy * wx * m_ * vy1 * vx1;                                 \
        WOUT = make_uint2((unsigned)f2h(w00) | ((unsigned)f2h(w01) << 16),    \
                          (unsigned)f2h(w10) | ((unsigned)f2h(w11) << 16));   \
        int ry0 = y0_ - hb, rx0 = x0_ - wb;                                   \
        if ((unsigned)ry0 <= 24u && (unsigned)rx0 <= 16u) {                   \
            EOUT = (unsigned)(ry0 * 18 + rx0) << 1;                           \
        } else {                                                              \
            int y0s = min(max(y0_, -8), 383) + 8;                             \
            int x0s = min(max(x0_, -8), 383) + 8;                             \
            EOUT = 1u | ((unsigned)y0s << 1) | ((unsigned)x0s << 10);         \
        }                                                                     \
    }
    {
        unsigned pe0, pe1, pe2 = 0;
        uint2 pw0 = make_uint2(0, 0), pw1 = pw0, pw2 = pw0;
        PARAMS(t, pe0, pw0);
        PARAMS(t + 512, pe1, pw1);
        if (t < 128) PARAMS(t + 1024, pe2, pw2);
        __syncthreads();               // all om_s reads done
        prmi[t] = pe0;        prmw_s[t] = pw0;
        prmi[t + 512] = pe1;  prmw_s[t + 512] = pw1;
        if (t < 128) { prmi[t + 1024] = pe2; prmw_s[t + 1024] = pw2; }
    }
#undef PARAMS
    __syncthreads();
    // ---- phase 3: tap loop — waves independent, zero barriers ----
    // Pipeline: q 1-deep (LOADC uses pi_n fetched a full iteration earlier — no
    // naked prm->address stall), prm 2-deep (t+2 issued under MFMA cover).

    f32x4 z = {0.f, 0.f, 0.f, 0.f};
    f32x4 acc[4] = {z, z, z, z};
    const half8* ap = (const half8*)wApack;
    uint4 q[4][2];                     // [corner][kk]

#define SBASE(CC) ((((CC) << 7) | (((CC) & 7u) << 4)) ^ lhi16)
#define LOADC(E)                                                              \
    {                                                                         \
        unsigned e_ = (E);                                                    \
        bool fb_ = (e_ & 1u);                                                 \
        unsigned cl_ = fb_ ? 0u : (e_ >> 1);                                  \
        unsigned a00 = SBASE(cl_), a01 = SBASE(cl_ + 1u);                     \
        unsigned a10 = SBASE(cl_ + 18u), a11 = SBASE(cl_ + 19u);              \
        q[0][0] = *(const uint4*)(halo + a00);                                \
        q[0][1] = *(const uint4*)(halo + (a00 ^ 64u));                        \
        q[1][0] = *(const uint4*)(halo + a01);                                \
        q[1][1] = *(const uint4*)(halo + (a01 ^ 64u));                        \
        q[2][0] = *(const uint4*)(halo + a10);                                \
        q[2][1] = *(const uint4*)(halo + (a10 ^ 64u));                        \
        q[3][0] = *(const uint4*)(halo + a11);                                \
        q[3][1] = *(const uint4*)(halo + (a11 ^ 64u));                        \
        if (__ballot(fb_)) {                                                  \
            if (fb_) {                                                        \
                int y0r = (int)((e_ >> 1) & 511) - 8;                         \
                int x0r = (int)((e_ >> 10) & 511) - 8;                        \
                int y0c = min(max(y0r, 0), 255), y1c = min(max(y0r + 1, 0), 255); \
                int x0c = min(max(x0r, 0), 255), x1c = min(max(x0r + 1, 0), 255); \
                const char* g00 = xbb + (((y0c << 8) + x0c) << 7) + (lhi << 4); \
                const char* g01 = xbb + (((y0c << 8) + x1c) << 7) + (lhi << 4); \
                const char* g10 = xbb + (((y1c << 8) + x0c) << 7) + (lhi << 4); \
                const char* g11 = xbb + (((y1c << 8) + x1c) << 7) + (lhi << 4); \
                q[0][0] = *(const uint4*)g00; q[0][1] = *(const uint4*)(g00 + 64); \
                q[1][0] = *(const uint4*)g01; q[1][1] = *(const uint4*)(g01 + 64); \
                q[2][0] = *(const uint4*)g10; q[2][1] = *(const uint4*)(g10 + 64); \
                q[3][0] = *(const uint4*)g11; q[3][1] = *(const uint4*)(g11 + 64); \
            }                                                                 \
        }                                                                     \
    }

    // prologue: q(0) in flight; prm(1) in flight
    unsigned pi_c = prmi[p];
    uint2 ww_c = prmw_s[p];
    LOADC(pi_c);
    unsigned pi_n = prmi[128 + p];
    uint2 ww_n = prmw_s[128 + p];

#pragma unroll
    for (int tap = 0; tap < 9; ++tap) {
        __half2 W00 = duph2(ww_c.x), W01 = duph2(ww_c.x >> 16);
        __half2 W10 = duph2(ww_c.y), W11 = duph2(ww_c.y >> 16);
        union HV { __half2 h2[4]; half8 h8; } V0, V1;
        __half2 z2 = __float2half2_rn(0.f);
#pragma unroll
        for (int j = 0; j < 4; ++j) { V0.h2[j] = z2; V1.h2[j] = z2; }
        hacc(q[0][0], W00, V0.h2); hacc(q[0][1], W00, V1.h2);
        hacc(q[1][0], W01, V0.h2); hacc(q[1][1], W01, V1.h2);
        hacc(q[2][0], W10, V0.h2); hacc(q[2][1], W10, V1.h2);
        hacc(q[3][0], W11, V0.h2); hacc(q[3][1], W11, V1.h2);
        half8 b0 = V0.h8, b1 = V1.h8;
        if (tap < 8) LOADC(pi_n);          // addresses ready: pi_n fetched last iter
        unsigned pi_t = 0;
        uint2 ww_t = make_uint2(0, 0);
        if (tap < 7) {                      // prm for tap+2 — covered by MFMA below
            pi_t = prmi[(tap + 2) * 128 + p];
            ww_t = prmw_s[(tap + 2) * 128 + p];
        }
        __builtin_amdgcn_s_setprio(1);
#pragma unroll
        for (int g2 = 0; g2 < 4; ++g2) {
            half8 a0 = ap[((g2 * 9 + tap) * 2 + 0) * 64 + lane];
            half8 a1 = ap[((g2 * 9 + tap) * 2 + 1) * 64 + lane];
            acc[g2] = __builtin_amdgcn_mfma_f32_16x16x32_f16(a0, b0, acc[g2], 0, 0, 0);
            acc[g2] = __builtin_amdgcn_mfma_f32_16x16x32_f16(a1, b1, acc[g2], 0, 0, 0);
        }
        __builtin_amdgcn_s_setprio(0);
        ww_c = ww_n;
        pi_n = pi_t;
        ww_n = ww_t;
    }
#undef LOADC
#undef SBASE

    // epilogue: preout (bf16, NCHW)
    unsigned short* pob = preout + (size_t)b * 64 * HWSZ;
    int gp = (h0 + (p >> 3)) * IMGW + w0 + (p & 7);
#pragma unroll
    for (int g2 = 0; g2 < 4; ++g2) {
#pragma unroll
        for (int jj = 0; jj < 4; ++jj) {
            int o = g2 * 16 + lhi * 4 + jj;
            pob[(size_t)o * HWSZ + gp] = f2bf(acc[g2][jj]);
        }
    }
    // BN partial stats
#pragma unroll
    for (int g2 = 0; g2 < 4; ++g2) {
#pragma unroll
        for (int jj = 0; jj < 4; ++jj) {
            float s1 = acc[g2][jj];
            float s2 = s1 * s1;
#pragma unroll
            for (int mask = 1; mask < 16; mask <<= 1) {
                s1 += __shfl_xor(s1, mask);
                s2 += __shfl_xor(s2, mask);
            }
            if (lp == 0) {
                int o = g2 * 16 + lhi * 4 + jj;
                atomicAdd(&bstats[o], s1);
                atomicAdd(&bstats[64 + o], s2);
            }
        }
    }
    __syncthreads();
    if (t < 128) atomicAdd(&stats[t], bstats[t]);
}

// ---------------- K3: normalize + relu + residual ----------------
__global__ __launch_bounds__(256) void bn_finalize(const float* __restrict__ stats,
                                                   const float* __restrict__ gamma,
                                                   const float* __restrict__ beta,
                                                   const float* __restrict__ x,
                                                   const unsigned short* __restrict__ preout,
                                                   float* __restrict__ out) {
    int i = blockIdx.x * 256 + threadIdx.x;     // uint4 idx over 8.4M bf16
    int e0 = i * 8;
    int o = (e0 >> 16) & 63;
    const float inv_n = 1.f / 131072.f;
    float mean = stats[o] * inv_n;
    float var = stats[64 + o] * inv_n - mean * mean;
    float rstd = rsqrtf(var + 1e-5f);
    float g = gamma[o] * rstd;
    float bb = beta[o] - mean * g;
    uint4 q = ((const uint4*)preout)[i];
    float4 x0 = ((const float4*)x)[i * 2];
    float4 x1 = ((const float4*)x)[i * 2 + 1];
    float4 r0, r1;
    r0.x = fmaxf(__uint_as_float(q.x << 16) * g + bb, 0.f) + x0.x;
    r0.y = fmaxf(__uint_as_float(q.x & 0xffff0000u) * g + bb, 0.f) + x0.y;
    r0.z = fmaxf(__uint_as_float(q.y << 16) * g + bb, 0.f) + x0.z;
    r0.w = fmaxf(__uint_as_float(q.y & 0xffff0000u) * g + bb, 0.f) + x0.w;
    r1.x = fmaxf(__uint_as_float(q.z << 16) * g + bb, 0.f) + x1.x;
    r1.y = fmaxf(__uint_as_float(q.z & 0xffff0000u) * g + bb, 0.f) + x1.y;
    r1.z = fmaxf(__uint_as_float(q.w << 16) * g + bb, 0.f) + x1.z;
    r1.w = fmaxf(__uint_as_float(q.w & 0xffff0000u) * g + bb, 0.f) + x1.w;
    ((float4*)out)[i * 2] = r0;
    ((float4*)out)[i * 2 + 1] = r1;
}

extern "C" void kernel_launch(void* const* d_in, const int* in_sizes, int n_in,
                              void* d_out, int out_size, void* d_ws, size_t ws_size,
                              hipStream_t stream) {
    const float* x     = (const float*)d_in[0];
    const float* w_off = (const float*)d_in[1];
    const float* b_off = (const float*)d_in[2];
    const float* w     = (const float*)d_in[3];
    const float* gamma = (const float*)d_in[5];
    const float* beta  = (const float*)d_in[6];
    float* out = (float*)d_out;
    char* wsb = (char*)d_ws;

    unsigned short* xT       = (unsigned short*)wsb;                    // 16,777,216 B (fp16)
    unsigned short* preout   = (unsigned short*)(wsb + 16777216);       // 16,777,216 B (bf16)
    unsigned short* wApack   = (unsigned short*)(wsb + 33554432);       // 73,728 B (fp16)
    unsigned short* wOffPack = (unsigned short*)(wsb + 33628160);       // 36,864 B (fp16)
    float*          stats    = (float*)(wsb + 33665024);                // 512 B

    hipMemsetAsync(stats, 0, 512, stream);
    prep_weights<<<216, 256, 0, stream>>>(w_off, w, wApack, wOffPack);
    transpose_x<<<2048, 256, 0, stream>>>(x, xT);
    dcn_main<<<1024, 512, 0, stream>>>(xT, wApack, wOffPack, b_off, preout, stats);
    bn_finalize<<<4096, 256, 0, stream>>>(stats, gamma, beta, x, preout, out);
}